// Round 11
// baseline (13218.959 us; speedup 1.0000x reference)
//
#include <hip/hip_runtime.h>
#include <math.h>

#define B 32
#define T 800
#define E 256
#define H 512
#define V 10000
#define S 100

typedef float f4 __attribute__((ext_vector_type(4)));

// ---- workspace float offsets ----
#define OFF_ENCP 0                          // [32][800][512]
#define OFF_GP   (OFF_ENCP + B*T*512)       // [4][32][2048] gates partials
#define OFF_ZB   (OFF_GP + 4*B*2048)        // [32][512] z
#define OFF_DECC (OFF_ZB + B*512)           // [2][32][512] cell parity
#define OFF_QV   (OFF_DECC + 2*B*512)       // [32][512]
#define OFF_PB   (OFF_QV + B*512)           // [32][800] p = exp(e)
#define OFF_PSL  (OFF_PB + B*T)             // [32][16] slice sums
#define OFF_CP   (OFF_PSL + B*16)           // [32][16][512] ctx partials
#define OFF_CTX  (OFF_CP + B*16*512)        // [32][512] ctx (feedback + logits)
#define OFF_KEY  (OFF_CTX + B*512)          // [2][32] u64 packed (mono(lmax), ~idx)
#define OFF_ESUM (OFF_KEY + 128)            // [2][32] sum exp(l)

__device__ __forceinline__ float tanh_fast(float x) {
    float e = __expf(2.0f * x);
    return 1.0f - __fdividef(2.0f, e + 1.0f);
}

// enc_proj = enc_pad @ W_enc (once)
__global__ __launch_bounds__(256) void k_encproj(const float* Ap, const float* Wenc, float* outp) {
    __shared__ float Ast[16][68];
    __shared__ float Bs[16][68];
    int rb = blockIdx.x, cb = blockIdx.y;
    int tid = threadIdx.x;
    int tx = tid & 15, ty = tid >> 4;
    float acc[4][4] = {};
    for (int kb = 0; kb < 32; kb++) {
        #pragma unroll
        for (int i = 0; i < 4; i++) {
            int idx = tid + i*256;
            int r = idx >> 4, k = idx & 15;
            Ast[k][r] = Ap[(rb*64 + r)*512 + kb*16 + k];
        }
        #pragma unroll
        for (int i = 0; i < 4; i++) {
            int idx = tid + i*256;
            int k = idx >> 6, c = idx & 63;
            Bs[k][c] = Wenc[(kb*16 + k)*512 + cb*64 + c];
        }
        __syncthreads();
        #pragma unroll
        for (int kk = 0; kk < 16; kk++) {
            f4 a4 = *(const f4*)&Ast[kk][ty*4];
            f4 b4 = *(const f4*)&Bs[kk][tx*4];
            #pragma unroll
            for (int i = 0; i < 4; i++)
                #pragma unroll
                for (int j = 0; j < 4; j++)
                    acc[i][j] += a4[i] * b4[j];
        }
        __syncthreads();
    }
    #pragma unroll
    for (int i = 0; i < 4; i++)
        #pragma unroll
        for (int j = 0; j < 4; j++)
            outp[(rb*64 + ty*4 + i)*512 + cb*64 + tx*4 + j] = acc[i][j];
}

__global__ __launch_bounds__(512) void k_init(float* ws) {
    int idx = blockIdx.x*512 + threadIdx.x;   // 32 blocks -> 16384
    ws[OFF_ZB + idx] = 0.f;
    ws[OFF_CTX + idx] = 0.f;
    ws[OFF_DECC + B*512 + idx] = 0.f;         // decc parity 1 (dold at s=0)
    if (blockIdx.x == 0 && threadIdx.x < 32) {
        unsigned long long* key = (unsigned long long*)(ws + OFF_KEY);
        key[32 + threadIdx.x] = 0xFFFFFFFEull;   // slot[1]: pred = BOS = 1
    }
}

// KA: gates partials. grid (64 j-tiles, 4 k-quarters), 512 thr.
// x staged in LDS; W streamed global->reg (each element read exactly once).
// LDS 75KB -> 2 blocks/CU. Also finalizes step s-1 outputs.
__global__ __launch_bounds__(512) void ka_gates(const float* __restrict__ Wih,
    const float* __restrict__ Whh, const float* __restrict__ emb,
    float* __restrict__ ws, float* __restrict__ outp, int s) {
    __shared__ float xs[32*324];
    __shared__ float part[8*32*33];
    __shared__ int preds[32];
    const int tid = threadIdx.x;
    const int jt = blockIdx.x, kq = blockIdx.y;
    const int p = s & 1;
    unsigned long long* keys = (unsigned long long*)(ws + OFF_KEY);
    float* esum = ws + OFF_ESUM;
    if (tid < 32) {
        unsigned long long k = keys[(p^1)*32 + tid];
        int pr = (int)(0xFFFFFFFFu - (unsigned)(k & 0xFFFFFFFFull));
        preds[tid] = pr;
        if (jt == 0 && kq == 0) {
            if (s > 0) {
                unsigned mu = (unsigned)(k >> 32);
                unsigned ou = (mu & 0x80000000u) ? (mu & 0x7FFFFFFFu) : ~mu;
                outp[tid*S + (s-1)] = __uint_as_float(ou) - logf(esum[(p^1)*32 + tid]);
                outp[B*S + tid*S + (s-1)] = (float)pr;
            }
            keys[p*32 + tid] = 0ull;
            esum[p*32 + tid] = 0.f;
        }
    }
    __syncthreads();
    const float* cbuf = ws + OFF_CTX;
    const float* zbuf = ws + OFF_ZB;
    // stage x quarter [32][320] (stride 324)
    #pragma unroll
    for (int i = 0; i < 5; i++) {
        int idx = tid + i*512;                // < 2560
        int b = idx / 80, c4 = idx - b*80;
        int k = kq*320 + c4*4;
        f4 v;
        if (k < 256)      v = *(const f4*)&emb[(size_t)preds[b]*E + k];
        else if (k < 768) v = *(const f4*)&cbuf[b*512 + (k-256)];
        else              v = *(const f4*)&zbuf[b*512 + (k-768)];
        *(f4*)&xs[b*324 + c4*4] = v;
    }
    __syncthreads();
    const int wid = tid >> 6, l = tid & 63;
    const int j0 = (l >> 3)*4, b0 = (l & 7)*4;
    const int ks0 = wid*40;
    float acc[4][4] = {};
    #pragma unroll 2
    for (int it = 0; it < 10; it++) {
        int k = ks0 + it*4;
        int kk = kq*320 + k;
        f4 w[4];
        if (kk < 768) {
            #pragma unroll
            for (int i = 0; i < 4; i++)
                w[i] = *(const f4*)&Wih[(size_t)(jt*32 + j0 + i)*768 + kk];
        } else {
            #pragma unroll
            for (int i = 0; i < 4; i++)
                w[i] = *(const f4*)&Whh[(size_t)(jt*32 + j0 + i)*512 + (kk - 768)];
        }
        f4 x[4];
        #pragma unroll
        for (int j = 0; j < 4; j++) x[j] = *(const f4*)&xs[(b0 + j)*324 + k];
        #pragma unroll
        for (int i = 0; i < 4; i++)
            #pragma unroll
            for (int j = 0; j < 4; j++)
                acc[i][j] += w[i][0]*x[j][0] + w[i][1]*x[j][1]
                           + w[i][2]*x[j][2] + w[i][3]*x[j][3];
    }
    __syncthreads();
    #pragma unroll
    for (int i = 0; i < 4; i++)
        #pragma unroll
        for (int j = 0; j < 4; j++)
            part[wid*1056 + (j0 + i)*33 + (b0 + j)] = acc[i][j];
    __syncthreads();
    #pragma unroll
    for (int u = 0; u < 2; u++) {
        int o = tid + u*512;                  // < 1024
        int j = o >> 5, b = o & 31;
        float g = 0.f;
        #pragma unroll
        for (int w2 = 0; w2 < 8; w2++) g += part[w2*1056 + j*33 + b];
        ws[OFF_GP + (kq*32 + b)*2048 + jt*32 + j] = g;
    }
}

// KQ: LSTM pointwise + q[b] = z[b] @ W_dec. 32 blocks (one per b).
__global__ __launch_bounds__(512) void kq_lstmq(const float* __restrict__ Wdec,
    const float* __restrict__ bih, const float* __restrict__ bhh,
    float* __restrict__ ws, int s) {
    __shared__ float zs[516];
    __shared__ float pq[4*516];
    const int tid = threadIdx.x, b = blockIdx.x;
    const int p = s & 1;
    const float* dold = ws + OFF_DECC + (p^1)*B*512;
    float* dnew = ws + OFF_DECC + p*B*512;
    {
        int h = tid;
        float gv[4];
        #pragma unroll
        for (int g = 0; g < 4; g++) {
            float sacc = bih[g*512 + h] + bhh[g*512 + h];
            #pragma unroll
            for (int kc = 0; kc < 4; kc++)
                sacc += ws[OFF_GP + (kc*32 + b)*2048 + g*512 + h];
            gv[g] = sacc;
        }
        float ig = 1.f/(1.f + expf(-gv[0]));
        float fg = 1.f/(1.f + expf(-gv[1]));
        float g2 = tanhf(gv[2]);
        float og = 1.f/(1.f + expf(-gv[3]));
        float c = fg*dold[b*512 + h] + ig*g2;
        dnew[b*512 + h] = c;
        float z = og*tanhf(c);
        zs[h] = z;
        ws[OFF_ZB + b*512 + h] = z;
    }
    __syncthreads();
    {
        const int aq = tid & 127, ks = tid >> 7;
        const int a0 = aq*4;
        f4 accq = {0.f, 0.f, 0.f, 0.f};
        #pragma unroll 4
        for (int kk = 0; kk < 128; kk += 4) {
            int k = ks*128 + kk;
            f4 z4 = *(const f4*)&zs[k];
            f4 w0 = *(const f4*)&Wdec[(size_t)(k+0)*512 + a0];
            f4 w1 = *(const f4*)&Wdec[(size_t)(k+1)*512 + a0];
            f4 w2 = *(const f4*)&Wdec[(size_t)(k+2)*512 + a0];
            f4 w3 = *(const f4*)&Wdec[(size_t)(k+3)*512 + a0];
            accq += z4[0]*w0 + z4[1]*w1 + z4[2]*w2 + z4[3]*w3;
        }
        *(f4*)&pq[ks*516 + a0] = accq;
    }
    __syncthreads();
    {
        int a = tid;
        float q = pq[a] + pq[516 + a] + pq[2*516 + a] + pq[3*516 + a];
        ws[OFF_QV + b*512 + a] = q;
    }
}

// KB: streaming e/p + ctx partials. 512 blocks = b*16 + ts (50 t each), 512 thr.
__global__ __launch_bounds__(512) void kb_ectx(const float* __restrict__ encpad,
    const float* __restrict__ vatt, const int* __restrict__ enclen,
    float* __restrict__ ws) {
    __shared__ float qs[512];
    __shared__ float vs[512];
    __shared__ float ep[50*132];          // e partials [t][c4]; reused for ctx f4 partials
    __shared__ float p8[64][9];
    __shared__ float pl[52];
    const int tid = threadIdx.x;
    const int b = blockIdx.x >> 4, ts = blockIdx.x & 15;
    const int len = enclen[b];
    const int t0 = ts*50;
    const int nt = min(t0 + 50, len) - t0;   // may be <=0
    qs[tid] = ws[OFF_QV + b*512 + tid];
    vs[tid] = vatt[tid];
    if (tid < 52) pl[tid] = 0.f;
    if (tid < 50) ws[OFF_PB + b*800 + t0 + tid] = 0.f;
    __syncthreads();
    const int c4 = tid & 127, tg = tid >> 7;
    const f4 q4 = *(const f4*)&qs[c4*4];
    const f4 vv = *(const f4*)&vs[c4*4];
    // phase e: partial per (t, c4)
    #pragma unroll
    for (int k = 0; k < 13; k++) {
        int tt = tg + 4*k;
        if (tt < nt) {
            f4 e4 = *(const f4*)&ws[OFF_ENCP + ((size_t)(b*800 + t0 + tt))*512 + c4*4];
            float sv = tanh_fast(e4[0]+q4[0])*vv[0] + tanh_fast(e4[1]+q4[1])*vv[1]
                     + tanh_fast(e4[2]+q4[2])*vv[2] + tanh_fast(e4[3]+q4[3])*vv[3];
            ep[tt*132 + c4] = sv;
        }
    }
    __syncthreads();
    // reduce 128 -> 8
    {
        int t = tid >> 3, j = tid & 7;
        if (t < nt) {
            float sv = 0.f;
            #pragma unroll
            for (int m = 0; m < 16; m++) sv += ep[t*132 + j*16 + m];
            p8[t][j] = sv;
        }
    }
    __syncthreads();
    if (tid < nt) {
        float e = 0.f;
        #pragma unroll
        for (int j = 0; j < 8; j++) e += p8[tid][j];
        float pv = __expf(e);
        pl[tid] = pv;
        ws[OFF_PB + b*800 + t0 + tid] = pv;
    }
    __syncthreads();
    if (tid == 0) {
        float sacc = 0.f;
        for (int i = 0; i < 50; i++) sacc += pl[i];
        ws[OFF_PSL + b*16 + ts] = sacc;
    }
    // phase ctx: f4 partial per (c4, tg)
    f4 acc = {0.f, 0.f, 0.f, 0.f};
    #pragma unroll
    for (int k = 0; k < 13; k++) {
        int tt = tg + 4*k;
        if (tt < nt) {
            f4 e4 = *(const f4*)&encpad[((size_t)(b*800 + t0 + tt))*512 + c4*4];
            acc += pl[tt]*e4;
        }
    }
    __syncthreads();
    *(f4*)&ep[(tg*128 + c4)*4] = acc;
    __syncthreads();
    if (tid < 128) {
        f4 c = {0.f, 0.f, 0.f, 0.f};
        #pragma unroll
        for (int g = 0; g < 4; g++) c += *(const f4*)&ep[(g*128 + tid)*4];
        *(f4*)&ws[OFF_CP + (size_t)(b*16 + ts)*512 + tid*4] = c;
    }
}

// KR: ctx 16-way reduce + attention-weight output. 32 blocks (b).
__global__ __launch_bounds__(512) void kr_ctx(float* __restrict__ ws,
    float* __restrict__ outp, int s) {
    const int tid = threadIdx.x, b = blockIdx.x;
    __shared__ float invs;
    if (tid == 0) {
        float sacc = 0.f;
        #pragma unroll
        for (int i = 0; i < 16; i++) sacc += ws[OFF_PSL + b*16 + i];
        invs = 1.f / sacc;
    }
    __syncthreads();
    float inv = invs;
    {
        float c = 0.f;
        #pragma unroll
        for (int t2 = 0; t2 < 16; t2++) c += ws[OFF_CP + (size_t)(b*16 + t2)*512 + tid];
        ws[OFF_CTX + b*512 + tid] = c * inv;
    }
    float* wrow = outp + 2*B*S + (size_t)(b*S + s)*T;
    for (int t = tid; t < 800; t += 512)
        wrow[t] = ws[OFF_PB + b*800 + t] * inv;
}

// KC: logits. 500 blocks x 20 v-rows, 512 thr, NO x-staging (y is L2-resident),
// LDS = 21KB partials only -> multiple blocks/CU. K-split 8x128 (bit-identical
// per-logit accumulation order to the round-7 kernel). Fused argmax/sumexp.
__global__ __launch_bounds__(512) void kc_logits(const float* __restrict__ Wout,
    const float* __restrict__ bout, float* __restrict__ ws, int s) {
    __shared__ float part[8*660];
    const int tid = threadIdx.x, blk = blockIdx.x;
    const int p = s & 1;
    const int v0 = blk*20;
    const int wid = tid >> 6, l = tid & 63;
    const int vq = l & 3, bq2 = l >> 2;       // 4 v-groups x 16 b
    float acc[5][2] = {};
    const int kb = wid*128;
    const float* wbase = &Wout[(size_t)(v0 + vq*5)*1024 + kb];
    const float* xz = ws + OFF_ZB;
    const float* xc = ws + OFF_CTX;
    #pragma unroll 2
    for (int g = 0; g < 32; g++) {
        f4 w[5];
        #pragma unroll
        for (int i = 0; i < 5; i++) w[i] = *(const f4*)&wbase[i*1024 + g*4];
        #pragma unroll
        for (int j = 0; j < 2; j++) {
            int bb = bq2 + 16*j;
            f4 x4 = (kb < 512) ? *(const f4*)&xz[bb*512 + kb + g*4]
                               : *(const f4*)&xc[bb*512 + (kb - 512) + g*4];
            #pragma unroll
            for (int i = 0; i < 5; i++)
                acc[i][j] += w[i][0]*x4[0] + w[i][1]*x4[1] + w[i][2]*x4[2] + w[i][3]*x4[3];
        }
    }
    #pragma unroll
    for (int i = 0; i < 5; i++)
        #pragma unroll
        for (int j = 0; j < 2; j++)
            part[wid*660 + (vq*5 + i)*33 + (bq2 + 16*j)] = acc[i][j];
    __syncthreads();
    if (tid < 128) {
        int b = tid >> 2, u = tid & 3;
        float bmax = -3.0e38f; int bidx = 0; float bsum = 0.f;
        #pragma unroll
        for (int i = 0; i < 5; i++) {
            int r = u*5 + i;
            float lv = bout[v0 + r];
            #pragma unroll
            for (int w2 = 0; w2 < 8; w2++) lv += part[w2*660 + r*33 + b];
            bsum += __expf(lv);
            if (lv > bmax) { bmax = lv; bidx = v0 + r; }
        }
        #pragma unroll
        for (int off = 1; off < 4; off <<= 1) {
            float ov = __shfl_xor(bmax, off, 64);
            int oi = __shfl_xor(bidx, off, 64);
            float os = __shfl_xor(bsum, off, 64);
            bsum += os;
            if (ov > bmax || (ov == bmax && oi < bidx)) { bmax = ov; bidx = oi; }
        }
        if (u == 0) {
            unsigned mu = __float_as_uint(bmax);
            mu = (mu & 0x80000000u) ? ~mu : (mu | 0x80000000u);
            unsigned long long kk = ((unsigned long long)mu << 32)
                                  | (unsigned long long)(0xFFFFFFFFu - (unsigned)bidx);
            atomicMax((unsigned long long*)(ws + OFF_KEY) + p*32 + b, kk);
            atomicAdd(ws + OFF_ESUM + p*32 + b, bsum);
        }
    }
}

__global__ __launch_bounds__(64) void k_final(float* __restrict__ ws, float* __restrict__ outp) {
    int b = threadIdx.x;
    if (b < 32) {
        unsigned long long k = ((unsigned long long*)(ws + OFF_KEY))[32 + b];  // p(99)=1
        unsigned mu = (unsigned)(k >> 32);
        unsigned ou = (mu & 0x80000000u) ? (mu & 0x7FFFFFFFu) : ~mu;
        int pr = (int)(0xFFFFFFFFu - (unsigned)(k & 0xFFFFFFFFull));
        outp[b*S + 99] = __uint_as_float(ou) - logf(ws[OFF_ESUM + 32 + b]);
        outp[B*S + b*S + 99] = (float)pr;
    }
}

extern "C" void kernel_launch(void* const* d_in, const int* in_sizes, int n_in,
                              void* d_out, int out_size, void* d_ws, size_t ws_size,
                              hipStream_t stream) {
    (void)in_sizes; (void)n_in; (void)out_size; (void)ws_size;
    const float* encpad = (const float*)d_in[0];
    const float* emb    = (const float*)d_in[1];
    const float* Wih    = (const float*)d_in[2];
    const float* Whh    = (const float*)d_in[3];
    const float* bih    = (const float*)d_in[4];
    const float* bhh    = (const float*)d_in[5];
    const float* Wenc   = (const float*)d_in[6];
    const float* Wdec   = (const float*)d_in[7];
    const float* vatt   = (const float*)d_in[8];
    const float* Wout   = (const float*)d_in[9];
    const float* bout   = (const float*)d_in[10];
    const int*   enclen = (const int*)d_in[11];
    float* outp = (float*)d_out;
    float* ws   = (float*)d_ws;

    k_init<<<32, 512, 0, stream>>>(ws);
    k_encproj<<<dim3(400, 8), 256, 0, stream>>>(encpad, Wenc, ws + OFF_ENCP);

    for (int s = 0; s < S; s++) {
        ka_gates<<<dim3(64, 4), 512, 0, stream>>>(Wih, Whh, emb, ws, outp, s);
        kq_lstmq<<<32, 512, 0, stream>>>(Wdec, bih, bhh, ws, s);
        kb_ectx<<<512, 512, 0, stream>>>(encpad, vatt, enclen, ws);
        kr_ctx<<<32, 512, 0, stream>>>(ws, outp, s);
        kc_logits<<<500, 512, 0, stream>>>(Wout, bout, ws, s);
    }
    k_final<<<1, 64, 0, stream>>>(ws, outp);
}

// Round 12
// 7913.415 us; speedup vs baseline: 1.6704x; 1.6704x over previous
//
#include <hip/hip_runtime.h>
#include <math.h>

#define B 32
#define T 800
#define E 256
#define H 512
#define V 10000
#define S 100

typedef float f4 __attribute__((ext_vector_type(4)));

// ---- workspace float offsets ----
#define OFF_ENCP 0                          // [32][800][512]
#define OFF_GP   (OFF_ENCP + B*T*512)       // [4][32][2048] gates partials
#define OFF_ZB   (OFF_GP + 4*B*2048)        // [32][512] z
#define OFF_DECC (OFF_ZB + B*512)           // [2][32][512] cell parity
#define OFF_QV   (OFF_DECC + 2*B*512)       // [32][512]
#define OFF_PB   (OFF_QV + B*512)           // [32][800] p = exp(e)
#define OFF_PSL  (OFF_PB + B*T)             // [32][16] slice sums
#define OFF_CP   (OFF_PSL + B*16)           // [32][16][512] ctx partials
#define OFF_CTX  (OFF_CP + B*16*512)        // [32][512] ctx (feedback + logits)
#define OFF_KEY  (OFF_CTX + B*512)          // [2][32] u64 packed (mono(lmax), ~idx)
#define OFF_ESUM (OFF_KEY + 128)            // [2][32] sum exp(l)

__device__ __forceinline__ float tanh_fast(float x) {
    float e = __expf(2.0f * x);
    return 1.0f - __fdividef(2.0f, e + 1.0f);
}

// enc_proj = enc_pad @ W_enc (once)
__global__ __launch_bounds__(256) void k_encproj(const float* Ap, const float* Wenc, float* outp) {
    __shared__ float Ast[16][68];
    __shared__ float Bs[16][68];
    int rb = blockIdx.x, cb = blockIdx.y;
    int tid = threadIdx.x;
    int tx = tid & 15, ty = tid >> 4;
    float acc[4][4] = {};
    for (int kb = 0; kb < 32; kb++) {
        #pragma unroll
        for (int i = 0; i < 4; i++) {
            int idx = tid + i*256;
            int r = idx >> 4, k = idx & 15;
            Ast[k][r] = Ap[(rb*64 + r)*512 + kb*16 + k];
        }
        #pragma unroll
        for (int i = 0; i < 4; i++) {
            int idx = tid + i*256;
            int k = idx >> 6, c = idx & 63;
            Bs[k][c] = Wenc[(kb*16 + k)*512 + cb*64 + c];
        }
        __syncthreads();
        #pragma unroll
        for (int kk = 0; kk < 16; kk++) {
            f4 a4 = *(const f4*)&Ast[kk][ty*4];
            f4 b4 = *(const f4*)&Bs[kk][tx*4];
            #pragma unroll
            for (int i = 0; i < 4; i++)
                #pragma unroll
                for (int j = 0; j < 4; j++)
                    acc[i][j] += a4[i] * b4[j];
        }
        __syncthreads();
    }
    #pragma unroll
    for (int i = 0; i < 4; i++)
        #pragma unroll
        for (int j = 0; j < 4; j++)
            outp[(rb*64 + ty*4 + i)*512 + cb*64 + tx*4 + j] = acc[i][j];
}

__global__ __launch_bounds__(512) void k_init(float* ws) {
    int idx = blockIdx.x*512 + threadIdx.x;   // 32 blocks -> 16384
    ws[OFF_ZB + idx] = 0.f;
    ws[OFF_CTX + idx] = 0.f;
    ws[OFF_DECC + B*512 + idx] = 0.f;         // decc parity 1 (dold at s=0)
    if (blockIdx.x == 0 && threadIdx.x < 32) {
        unsigned long long* key = (unsigned long long*)(ws + OFF_KEY);
        key[32 + threadIdx.x] = 0xFFFFFFFEull;   // slot[1]: pred = BOS = 1
    }
}

// KA: gates partials. grid (64 j-tiles, 4 k-quarters), 512 thr, LDS-staged W+x.
// (round-7 verbatim) Also finalizes step s-1 outputs.
__global__ __launch_bounds__(512) void ka_gates(const float* __restrict__ Wih,
    const float* __restrict__ Whh, const float* __restrict__ emb,
    float* __restrict__ ws, float* __restrict__ outp, int s) {
    __shared__ float xs[32*324];
    __shared__ float wt[32*324];
    __shared__ float part[8*32*33];
    __shared__ int preds[32];
    const int tid = threadIdx.x;
    const int jt = blockIdx.x, kq = blockIdx.y;
    const int p = s & 1;
    unsigned long long* keys = (unsigned long long*)(ws + OFF_KEY);
    float* esum = ws + OFF_ESUM;
    if (tid < 32) {
        unsigned long long k = keys[(p^1)*32 + tid];
        int pr = (int)(0xFFFFFFFFu - (unsigned)(k & 0xFFFFFFFFull));
        preds[tid] = pr;
        if (jt == 0 && kq == 0) {
            if (s > 0) {
                unsigned mu = (unsigned)(k >> 32);
                unsigned ou = (mu & 0x80000000u) ? (mu & 0x7FFFFFFFu) : ~mu;
                outp[tid*S + (s-1)] = __uint_as_float(ou) - logf(esum[(p^1)*32 + tid]);
                outp[B*S + tid*S + (s-1)] = (float)pr;
            }
            keys[p*32 + tid] = 0ull;
            esum[p*32 + tid] = 0.f;
        }
    }
    __syncthreads();
    const float* cbuf = ws + OFF_CTX;
    const float* zbuf = ws + OFF_ZB;
    // stage x quarter [32][320] (stride 324)
    #pragma unroll
    for (int i = 0; i < 5; i++) {
        int idx = tid + i*512;                // < 2560
        int b = idx / 80, c4 = idx - b*80;
        int k = kq*320 + c4*4;
        f4 v;
        if (k < 256)      v = *(const f4*)&emb[(size_t)preds[b]*E + k];
        else if (k < 768) v = *(const f4*)&cbuf[b*512 + (k-256)];
        else              v = *(const f4*)&zbuf[b*512 + (k-768)];
        *(f4*)&xs[b*324 + c4*4] = v;
    }
    // stage W tile [32 rows][320 k] (stride 324), coalesced, no redundancy
    #pragma unroll
    for (int i = 0; i < 5; i++) {
        int idx = tid + i*512;                // < 2560
        int r = idx / 80, c4 = idx - r*80;
        int kk = kq*320 + c4*4;
        int j = jt*32 + r;
        f4 v = (kk < 768) ? *(const f4*)&Wih[(size_t)j*768 + kk]
                          : *(const f4*)&Whh[(size_t)j*512 + (kk - 768)];
        *(f4*)&wt[r*324 + c4*4] = v;
    }
    __syncthreads();
    const int wid = tid >> 6, l = tid & 63;
    const int j0 = (l >> 3)*4, b0 = (l & 7)*4;
    const int ks0 = wid*40;
    float acc[4][4] = {};
    #pragma unroll 2
    for (int it = 0; it < 10; it++) {
        int k = ks0 + it*4;
        f4 w[4], x[4];
        #pragma unroll
        for (int i = 0; i < 4; i++) w[i] = *(const f4*)&wt[(j0 + i)*324 + k];
        #pragma unroll
        for (int j = 0; j < 4; j++) x[j] = *(const f4*)&xs[(b0 + j)*324 + k];
        #pragma unroll
        for (int i = 0; i < 4; i++)
            #pragma unroll
            for (int j = 0; j < 4; j++)
                acc[i][j] += w[i][0]*x[j][0] + w[i][1]*x[j][1]
                           + w[i][2]*x[j][2] + w[i][3]*x[j][3];
    }
    __syncthreads();
    #pragma unroll
    for (int i = 0; i < 4; i++)
        #pragma unroll
        for (int j = 0; j < 4; j++)
            part[wid*1056 + (j0 + i)*33 + (b0 + j)] = acc[i][j];
    __syncthreads();
    #pragma unroll
    for (int u = 0; u < 2; u++) {
        int o = tid + u*512;                  // < 1024
        int j = o >> 5, b = o & 31;
        float g = 0.f;
        #pragma unroll
        for (int w2 = 0; w2 < 8; w2++) g += part[w2*1056 + j*33 + b];
        ws[OFF_GP + (kq*32 + b)*2048 + jt*32 + j] = g;
    }
}

// KQ: LSTM pointwise (redundant x8, bit-identical; as==0 writes state) +
// q a-slice: grid (32 b, 8 a-slices of 64), W_dec panel 128KB/block, z in LDS.
__global__ __launch_bounds__(512) void kq_lstmq(const float* __restrict__ Wdec,
    const float* __restrict__ bih, const float* __restrict__ bhh,
    float* __restrict__ ws, int s) {
    __shared__ float zs[516];
    __shared__ float pq[32*68];
    const int tid = threadIdx.x;
    const int b = blockIdx.x, as = blockIdx.y;
    const int p = s & 1;
    const float* dold = ws + OFF_DECC + (p^1)*B*512;
    float* dnew = ws + OFF_DECC + p*B*512;
    {
        int h = tid;
        float gv[4];
        #pragma unroll
        for (int g = 0; g < 4; g++) {
            float sacc = bih[g*512 + h] + bhh[g*512 + h];
            #pragma unroll
            for (int kc = 0; kc < 4; kc++)
                sacc += ws[OFF_GP + (kc*32 + b)*2048 + g*512 + h];
            gv[g] = sacc;
        }
        float ig = 1.f/(1.f + expf(-gv[0]));
        float fg = 1.f/(1.f + expf(-gv[1]));
        float g2 = tanhf(gv[2]);
        float og = 1.f/(1.f + expf(-gv[3]));
        float c = fg*dold[b*512 + h] + ig*g2;
        float z = og*tanhf(c);
        zs[h] = z;
        if (as == 0) {
            dnew[b*512 + h] = c;
            ws[OFF_ZB + b*512 + h] = z;
        }
    }
    __syncthreads();
    {
        const int aq = tid & 15, ks = tid >> 4;   // 16 f4-groups x 32 k-splits
        const int a0 = as*64 + aq*4;
        f4 accq = {0.f, 0.f, 0.f, 0.f};
        #pragma unroll
        for (int kk = 0; kk < 16; kk += 4) {
            int k = ks*16 + kk;
            f4 z4 = *(const f4*)&zs[k];
            f4 w0 = *(const f4*)&Wdec[(size_t)(k+0)*512 + a0];
            f4 w1 = *(const f4*)&Wdec[(size_t)(k+1)*512 + a0];
            f4 w2 = *(const f4*)&Wdec[(size_t)(k+2)*512 + a0];
            f4 w3 = *(const f4*)&Wdec[(size_t)(k+3)*512 + a0];
            accq += z4[0]*w0 + z4[1]*w1 + z4[2]*w2 + z4[3]*w3;
        }
        *(f4*)&pq[ks*68 + aq*4] = accq;
    }
    __syncthreads();
    if (tid < 64) {
        float q = 0.f;
        #pragma unroll
        for (int ks = 0; ks < 32; ks++) q += pq[ks*68 + tid];
        ws[OFF_QV + b*512 + as*64 + tid] = q;
    }
}

// KB: streaming e/p + ctx partials. 512 blocks = b*16 + ts (50 t each), 512 thr.
__global__ __launch_bounds__(512) void kb_ectx(const float* __restrict__ encpad,
    const float* __restrict__ vatt, const int* __restrict__ enclen,
    float* __restrict__ ws) {
    __shared__ float qs[512];
    __shared__ float vs[512];
    __shared__ float ep[50*132];          // e partials [t][c4]; reused for ctx f4 partials
    __shared__ float p8[64][9];
    __shared__ float pl[52];
    const int tid = threadIdx.x;
    const int b = blockIdx.x >> 4, ts = blockIdx.x & 15;
    const int len = enclen[b];
    const int t0 = ts*50;
    const int nt = min(t0 + 50, len) - t0;   // may be <=0
    qs[tid] = ws[OFF_QV + b*512 + tid];
    vs[tid] = vatt[tid];
    if (tid < 52) pl[tid] = 0.f;
    if (tid < 50) ws[OFF_PB + b*800 + t0 + tid] = 0.f;
    __syncthreads();
    const int c4 = tid & 127, tg = tid >> 7;
    const f4 q4 = *(const f4*)&qs[c4*4];
    const f4 vv = *(const f4*)&vs[c4*4];
    // phase e: partial per (t, c4)
    #pragma unroll
    for (int k = 0; k < 13; k++) {
        int tt = tg + 4*k;
        if (tt < nt) {
            f4 e4 = *(const f4*)&ws[OFF_ENCP + ((size_t)(b*800 + t0 + tt))*512 + c4*4];
            float sv = tanh_fast(e4[0]+q4[0])*vv[0] + tanh_fast(e4[1]+q4[1])*vv[1]
                     + tanh_fast(e4[2]+q4[2])*vv[2] + tanh_fast(e4[3]+q4[3])*vv[3];
            ep[tt*132 + c4] = sv;
        }
    }
    __syncthreads();
    // reduce 128 -> 8
    {
        int t = tid >> 3, j = tid & 7;
        if (t < nt) {
            float sv = 0.f;
            #pragma unroll
            for (int m = 0; m < 16; m++) sv += ep[t*132 + j*16 + m];
            p8[t][j] = sv;
        }
    }
    __syncthreads();
    if (tid < nt) {
        float e = 0.f;
        #pragma unroll
        for (int j = 0; j < 8; j++) e += p8[tid][j];
        float pv = __expf(e);
        pl[tid] = pv;
        ws[OFF_PB + b*800 + t0 + tid] = pv;
    }
    __syncthreads();
    if (tid == 0) {
        float sacc = 0.f;
        for (int i = 0; i < 50; i++) sacc += pl[i];
        ws[OFF_PSL + b*16 + ts] = sacc;
    }
    // phase ctx: f4 partial per (c4, tg)
    f4 acc = {0.f, 0.f, 0.f, 0.f};
    #pragma unroll
    for (int k = 0; k < 13; k++) {
        int tt = tg + 4*k;
        if (tt < nt) {
            f4 e4 = *(const f4*)&encpad[((size_t)(b*800 + t0 + tt))*512 + c4*4];
            acc += pl[tt]*e4;
        }
    }
    __syncthreads();
    *(f4*)&ep[(tg*128 + c4)*4] = acc;
    __syncthreads();
    if (tid < 128) {
        f4 c = {0.f, 0.f, 0.f, 0.f};
        #pragma unroll
        for (int g = 0; g < 4; g++) c += *(const f4*)&ep[(g*128 + tid)*4];
        *(f4*)&ws[OFF_CP + (size_t)(b*16 + ts)*512 + tid*4] = c;
    }
}

// KR: ctx 16-way reduce + attention-weight output. 32 blocks (b).
__global__ __launch_bounds__(512) void kr_ctx(float* __restrict__ ws,
    float* __restrict__ outp, int s) {
    const int tid = threadIdx.x, b = blockIdx.x;
    __shared__ float invs;
    if (tid == 0) {
        float sacc = 0.f;
        #pragma unroll
        for (int i = 0; i < 16; i++) sacc += ws[OFF_PSL + b*16 + i];
        invs = 1.f / sacc;
    }
    __syncthreads();
    float inv = invs;
    {
        float c = 0.f;
        #pragma unroll
        for (int t2 = 0; t2 < 16; t2++) c += ws[OFF_CP + (size_t)(b*16 + t2)*512 + tid];
        ws[OFF_CTX + b*512 + tid] = c * inv;
    }
    float* wrow = outp + 2*B*S + (size_t)(b*S + s)*T;
    for (int t = tid; t < 800; t += 512)
        wrow[t] = ws[OFF_PB + b*800 + t] * inv;
}

// KC: logits (250 blocks: 40 v-rows x 32 b), x staged in LDS (round-7 verbatim),
// fused argmax/sumexp atomics.
__global__ __launch_bounds__(512) void kc_logits(const float* __restrict__ Wout,
    const float* __restrict__ bout, float* __restrict__ ws, int s) {
    __shared__ float sm[32*1028];
    const int tid = threadIdx.x, blk = blockIdx.x;
    const int p = s & 1;
    const int v0 = blk*40;
    #pragma unroll
    for (int i = 0; i < 8; i++) {
        int o = tid + i*512;                  // < 4096
        int bb = o >> 7, qq = o & 127;
        *(f4*)&sm[bb*1028 + qq*4] = *(const f4*)&ws[OFF_ZB + bb*512 + qq*4];
        *(f4*)&sm[bb*1028 + 512 + qq*4] = *(const f4*)&ws[OFF_CTX + bb*512 + qq*4];
    }
    __syncthreads();
    const int wid = tid >> 6, l = tid & 63;
    const int vq = l & 7, bq2 = l >> 3;
    float acc[5][4] = {};
    const int kb = wid*128;
    const float* wbase = &Wout[(size_t)(v0 + vq*5)*1024 + kb];
    #pragma unroll 2
    for (int g = 0; g < 32; g++) {
        f4 w[5];
        #pragma unroll
        for (int i = 0; i < 5; i++) w[i] = *(const f4*)&wbase[i*1024 + g*4];
        #pragma unroll
        for (int j = 0; j < 4; j++) {
            f4 x4 = *(const f4*)&sm[(bq2+8*j)*1028 + kb + g*4];
            #pragma unroll
            for (int i = 0; i < 5; i++)
                acc[i][j] += w[i][0]*x4[0] + w[i][1]*x4[1] + w[i][2]*x4[2] + w[i][3]*x4[3];
        }
    }
    __syncthreads();
    #pragma unroll
    for (int i = 0; i < 5; i++)
        #pragma unroll
        for (int j = 0; j < 4; j++)
            sm[wid*1320 + (vq*5+i)*33 + (bq2+8*j)] = acc[i][j];
    __syncthreads();
    if (tid < 256) {
        int b = tid >> 3, u = tid & 7;
        float bmax = -3.0e38f; int bidx = 0; float bsum = 0.f;
        #pragma unroll
        for (int i = 0; i < 5; i++) {
            int r = u*5 + i;
            float lv = bout[v0 + r];
            #pragma unroll
            for (int w2 = 0; w2 < 8; w2++) lv += sm[w2*1320 + r*33 + b];
            bsum += __expf(lv);
            if (lv > bmax) { bmax = lv; bidx = v0 + r; }
        }
        #pragma unroll
        for (int off = 1; off < 8; off <<= 1) {
            float ov = __shfl_xor(bmax, off, 64);
            int oi = __shfl_xor(bidx, off, 64);
            float os = __shfl_xor(bsum, off, 64);
            bsum += os;
            if (ov > bmax || (ov == bmax && oi < bidx)) { bmax = ov; bidx = oi; }
        }
        if (u == 0) {
            unsigned mu = __float_as_uint(bmax);
            mu = (mu & 0x80000000u) ? ~mu : (mu | 0x80000000u);
            unsigned long long kk = ((unsigned long long)mu << 32)
                                  | (unsigned long long)(0xFFFFFFFFu - (unsigned)bidx);
            atomicMax((unsigned long long*)(ws + OFF_KEY) + p*32 + b, kk);
            atomicAdd(ws + OFF_ESUM + p*32 + b, bsum);
        }
    }
}

__global__ __launch_bounds__(64) void k_final(float* __restrict__ ws, float* __restrict__ outp) {
    int b = threadIdx.x;
    if (b < 32) {
        unsigned long long k = ((unsigned long long*)(ws + OFF_KEY))[32 + b];  // p(99)=1
        unsigned mu = (unsigned)(k >> 32);
        unsigned ou = (mu & 0x80000000u) ? (mu & 0x7FFFFFFFu) : ~mu;
        int pr = (int)(0xFFFFFFFFu - (unsigned)(k & 0xFFFFFFFFull));
        outp[b*S + 99] = __uint_as_float(ou) - logf(ws[OFF_ESUM + 32 + b]);
        outp[B*S + b*S + 99] = (float)pr;
    }
}

extern "C" void kernel_launch(void* const* d_in, const int* in_sizes, int n_in,
                              void* d_out, int out_size, void* d_ws, size_t ws_size,
                              hipStream_t stream) {
    (void)in_sizes; (void)n_in; (void)out_size; (void)ws_size;
    const float* encpad = (const float*)d_in[0];
    const float* emb    = (const float*)d_in[1];
    const float* Wih    = (const float*)d_in[2];
    const float* Whh    = (const float*)d_in[3];
    const float* bih    = (const float*)d_in[4];
    const float* bhh    = (const float*)d_in[5];
    const float* Wenc   = (const float*)d_in[6];
    const float* Wdec   = (const float*)d_in[7];
    const float* vatt   = (const float*)d_in[8];
    const float* Wout   = (const float*)d_in[9];
    const float* bout   = (const float*)d_in[10];
    const int*   enclen = (const int*)d_in[11];
    float* outp = (float*)d_out;
    float* ws   = (float*)d_ws;

    k_init<<<32, 512, 0, stream>>>(ws);
    k_encproj<<<dim3(400, 8), 256, 0, stream>>>(encpad, Wenc, ws + OFF_ENCP);

    for (int s = 0; s < S; s++) {
        ka_gates<<<dim3(64, 4), 512, 0, stream>>>(Wih, Whh, emb, ws, outp, s);
        kq_lstmq<<<dim3(32, 8), 512, 0, stream>>>(Wdec, bih, bhh, ws, s);
        kb_ectx<<<512, 512, 0, stream>>>(encpad, vatt, enclen, ws);
        kr_ctx<<<32, 512, 0, stream>>>(ws, outp, s);
        kc_logits<<<250, 512, 0, stream>>>(Wout, bout, ws, s);
    }
    k_final<<<1, 64, 0, stream>>>(ws, outp);
}